// Round 6
// baseline (848.408 us; speedup 1.0000x reference)
//
#include <hip/hip_runtime.h>

// Problem constants: B,S,NODE,DEP,R,L,E = 32,1024,256,64,50,16,128
constexpr int B_ = 32;
constexpr int S_ = 1024;
constexpr int NODE_ = 256;
constexpr int DEP_ = 64;
constexpr int R_ = 50;
constexpr int L_ = 16;
constexpr int E_ = 128;
constexpr int FEAT_ = NODE_ + DEP_;     // 320
constexpr int NEDGE_ = B_ * E_;         // 4096 edges per layer
constexpr int BS_ = B_ * S_;            // 32768 rows
constexpr int CH_ = 16;                 // edges per relation-chunk (chain)
constexpr int NCH_ = 320;               // sum ceil(n_r/16) <= 306
constexpr int PREB_ = 512;              // worker blocks in k_pre
constexpr int GCH_ = 64;                // edges per GLOBAL relation-chunk (k_ctx2)
constexpr int NGC_ = 1088;              // >= 50 + 65536/64 = 1074
constexpr int SLOTCAP_ = 4096;          // max touched rows per layer (<= NEDGE_)

// ---------------------------------------------------------------------------
// Key algebra: msg = W[r][:,0:256]@ctx[t] + W[r][:,256:320]@childval[t].
// ctx term + index metadata precomputed in k_ctx2 (relation-binned ACROSS
// layers -> 64x64x256 register-tiled GEMM per block; ctxdot in g-order).
// r6 structural change: per-layer COMPACT accumulators Acmp[l][slot][64]
// (slot = dense rank of touched row in layer l). "Latest child state" is
// resolved at PRECOMPUTE time into per-edge gather indices:
//   m_src[pos] = (l*<<12)+slot of latest earlier layer touching tail, or -1
//   m_hsl[pos] = scatter slot at own layer
//   out_l[row]/slot_lr = per-row latest layer for k_out
// -> the serial chain loses its copy(Aprev->child) and zero(Anext) phases
// entirely (r5 post-mortem: those sc-op phases, not the barrier, were the
// ~38us/layer cost). Layer-l* data is final after layer l* (each layer has
// its own buffer) -> gathers of finalized layers are race-free.
// Coherence (r4/r5-proven): atomics at PoC; gathers LD_SC (PoC-direct);
// barrier = contention-free arrive[]/done release/acquire flags; read-only
// tables plain/cached. Dispatch boundaries cover pre/ctx2/out transitions.
// ---------------------------------------------------------------------------
constexpr size_t N_ACMP   = (size_t)L_ * SLOTCAP_ * DEP_;    // 4,194,304 floats
constexpr size_t OFF_WT   = N_ACMP;
constexpr size_t N_WT     = (size_t)R_ * FEAT_ * DEP_;       // 1,024,000
constexpr size_t OFF_SORT = OFF_WT + N_WT;
constexpr size_t N_SORT   = (size_t)L_ * NEDGE_;             // 65,536 ints
constexpr size_t OFF_CHUNK= OFF_SORT + N_SORT;
constexpr size_t N_CHUNK_I= (size_t)L_ * NCH_ * 4;           // ints
constexpr size_t OFF_HC   = OFF_CHUNK + N_CHUNK_I;
constexpr size_t N_HC     = (size_t)L_ * BS_;                // 524,288 ints
constexpr size_t OFF_MS   = OFF_HC + N_HC;                   // m_src
constexpr size_t OFF_MH   = OFF_MS + N_SORT;                 // m_hsl
constexpr size_t OFF_MI   = OFF_MH + N_SORT;                 // m_invc
constexpr size_t OFF_CD   = OFF_MI + N_SORT;                 // ctxdot (g-order)
constexpr size_t N_CD     = (size_t)L_ * NEDGE_ * DEP_;      // 4,194,304
constexpr size_t OFF_GIDX = OFF_CD + N_CD;                   // global bin: pos list
constexpr size_t OFF_GCH  = OFF_GIDX + N_SORT;               // int4 * NGC_
constexpr size_t OFF_HLR  = OFF_GCH + (size_t)NGC_ * 4;      // hist_lr [L*R] ints
constexpr size_t OFF_SLR  = OFF_HLR + (size_t)L_ * R_;       // start_lr [L*R] ints
constexpr size_t OFF_MG   = OFF_SLR + (size_t)L_ * R_;       // m_g: pos -> g
constexpr size_t OFF_SLOT = OFF_MG + N_SORT;                 // slot_lr [L][BS]
constexpr size_t OFF_OL   = OFF_SLOT + (size_t)L_ * BS_;     // out_l [BS]
constexpr size_t OFF_BAR  = OFF_OL + BS_;                    // done + arrive[NCH_]

#define LD_SC(p)    __hip_atomic_load((p), __ATOMIC_RELAXED, __HIP_MEMORY_SCOPE_AGENT)

// ---------------------------------------------------------------------------
// K_PRE: blocks 0..15 = per-layer relation binning + chunk table + head-count
// hist (publishes hist/start tables); blocks 16.. = W re-layout
// WT2[r][i4][k][c] + zero Acmp + out_l=-1 + barrier flags.
// ---------------------------------------------------------------------------
__global__ void k_pre(const float* __restrict__ W, const int* __restrict__ rels,
                      const int* __restrict__ heads,
                      float* __restrict__ WT2, int* __restrict__ sorted,
                      int4* __restrict__ chunks, int* __restrict__ hc,
                      float* __restrict__ Acmp,
                      int* __restrict__ hist_lr, int* __restrict__ start_lr,
                      int* __restrict__ out_l, int* __restrict__ bar) {
  int blk = blockIdx.x, tid = threadIdx.x;
  if (blk < L_) {
    int l = blk;
    __shared__ int hist[R_], startA[R_], rank[R_], cstart[R_];
    __shared__ int ntot;
    if (tid < R_) { hist[tid] = 0; rank[tid] = 0; }
    int* hcl = hc + (size_t)l * BS_;
    for (int i = tid; i < BS_; i += 256) hcl[i] = 0;
    __syncthreads();
    for (int ed = tid; ed < NEDGE_; ed += 256) {
      int b = ed >> 7, e = ed & (E_ - 1);
      atomicAdd(&hist[rels[(b * L_ + l) * E_ + e]], 1);
      atomicAdd(&hcl[b * S_ + heads[(b * L_ + l) * E_ + e]], 1);
    }
    __syncthreads();
    if (tid == 0) {
      int s = 0, cs = 0;
      for (int r = 0; r < R_; ++r) {
        startA[r] = s; s += hist[r];
        cstart[r] = cs; cs += (hist[r] + CH_ - 1) / CH_;
      }
      ntot = cs;
    }
    __syncthreads();
    for (int ed = tid; ed < NEDGE_; ed += 256) {
      int b = ed >> 7, e = ed & (E_ - 1);
      int r = rels[(b * L_ + l) * E_ + e];
      int pos = startA[r] + atomicAdd(&rank[r], 1);
      sorted[l * NEDGE_ + pos] = ed;
    }
    if (tid < R_) {
      hist_lr[l * R_ + tid] = hist[tid];
      start_lr[l * R_ + tid] = startA[tid];
      int n = hist[tid], st = startA[tid], cs = cstart[tid];
      for (int m = 0; m * CH_ < n; ++m) {
        int c = n - m * CH_; if (c > CH_) c = CH_;
        chunks[l * NCH_ + cs + m] = make_int4(tid, st + m * CH_, c, 0);
      }
    }
    __syncthreads();
    for (int i = ntot + tid; i < NCH_; i += 256)
      chunks[l * NCH_ + i] = make_int4(0, 0, 0, 0);
  } else {
    int gtid = (blk - L_) * 256 + tid;
    const int NT = PREB_ * 256;
    for (int i = gtid; i < 1 + NCH_; i += NT) bar[i] = 0;   // done + arrive[]
    for (int i = gtid; i < BS_; i += NT) out_l[i] = -1;
    for (int gid = gtid; gid < (int)N_WT; gid += NT) {
      int r = gid / 20480;           // 80*64*4
      int rem = gid - r * 20480;
      int i4 = rem >> 8;
      int k = (rem >> 2) & 63;
      int c = rem & 3;
      WT2[gid] = W[((size_t)r * DEP_ + k) * FEAT_ + 4 * i4 + c];
    }
    float4* z4 = (float4*)Acmp;
    int nz4 = (int)(N_ACMP / 4);
    for (int i = gtid; i < nz4; i += NT) z4[i] = make_float4(0.f, 0.f, 0.f, 0.f);
  }
}

// ---------------------------------------------------------------------------
// K_GIDX: blocks 0..799 = one per (r,l) run: redundantly compute global
// r-grouped offsets from the hist table, copy the run into gidx; block 0
// also emits the global chunk table. Blocks 800..815 = one per layer:
// dense slot ranks (slot_lr[l][row] = rank among touched rows) + per-row
// latest-touching-layer via atomicMax(out_l).
// ---------------------------------------------------------------------------
__global__ void __launch_bounds__(256) k_gidx(
    const int* __restrict__ hist_lr, const int* __restrict__ start_lr,
    const int* __restrict__ hc,
    int* __restrict__ gidx, int4* __restrict__ gchunks,
    int* __restrict__ slot_lr, int* __restrict__ out_l) {
  int bid = blockIdx.x, tid = threadIdx.x;
  if (bid >= R_ * L_) {
    // --- slot-rank blocks: one per layer ---
    int l = bid - R_ * L_;
    const int* hcl = hc + (size_t)l * BS_;
    int* sl = slot_lr + (size_t)l * BS_;
    __shared__ int psum[256];
    constexpr int RPT = BS_ / 256;       // 128 rows per thread
    int r0 = tid * RPT;
    int cnt = 0;
    for (int i = 0; i < RPT; ++i) cnt += (hcl[r0 + i] > 0) ? 1 : 0;
    psum[tid] = cnt;
    __syncthreads();
    if (tid == 0) {
      int s = 0;
      for (int i = 0; i < 256; ++i) { int c = psum[i]; psum[i] = s; s += c; }
    }
    __syncthreads();
    int base = psum[tid];
    for (int i = 0; i < RPT; ++i) {
      int row = r0 + i;
      if (hcl[row] > 0) { sl[row] = base++; atomicMax(&out_l[row], l); }
    }
    return;
  }
  int r = bid / L_, l = bid - r * L_;
  __shared__ int sh[L_ * R_];
  __shared__ int base_s, ntot_s;
  for (int i = tid; i < L_ * R_; i += 256) sh[i] = hist_lr[i];
  __syncthreads();
  if (tid == 0) {
    int goff = 0;
    for (int rr = 0; rr < r; ++rr)
      for (int ll = 0; ll < L_; ++ll) goff += sh[ll * R_ + rr];
    for (int ll = 0; ll < l; ++ll) goff += sh[ll * R_ + r];
    base_s = goff;
  }
  __syncthreads();
  int n = sh[l * R_ + r];
  int st = start_lr[l * R_ + r];
  int base = base_s;
  for (int i = tid; i < n; i += 256)
    gidx[base + i] = l * NEDGE_ + st + i;

  if (bid == 0) {
    __shared__ int tot[R_], goffA[R_], cstart[R_];
    if (tid < R_) {
      int t = 0;
      for (int ll = 0; ll < L_; ++ll) t += sh[ll * R_ + tid];
      tot[tid] = t;
    }
    __syncthreads();
    if (tid == 0) {
      int s = 0, cs = 0;
      for (int rr = 0; rr < R_; ++rr) {
        goffA[rr] = s; s += tot[rr];
        cstart[rr] = cs; cs += (tot[rr] + GCH_ - 1) / GCH_;
      }
      ntot_s = cs;
    }
    __syncthreads();
    if (tid < R_) {
      int nn = tot[tid], go = goffA[tid], cs = cstart[tid];
      for (int m = 0; m * GCH_ < nn; ++m) {
        int c = nn - m * GCH_; if (c > GCH_) c = GCH_;
        gchunks[cs + m] = make_int4(tid, go + m * GCH_, c, 0);
      }
    }
    __syncthreads();
    for (int i = ntot_s + tid; i < NGC_; i += 256)
      gchunks[i] = make_int4(0, 0, 0, 0);
  }
}

__device__ __forceinline__ float dot64(const float4* __restrict__ f4,
                                       const float4* __restrict__ w) {
  float a0 = 0.f, a1 = 0.f, a2 = 0.f, a3 = 0.f;
#pragma unroll
  for (int i = 0; i < 16; ++i) {
    float4 f = f4[i];
    a0 = fmaf(w[i].x, f.x, a0);
    a1 = fmaf(w[i].y, f.y, a1);
    a2 = fmaf(w[i].z, f.z, a2);
    a3 = fmaf(w[i].w, f.w, a3);
  }
  return (a0 + a1) + (a2 + a3);
}

__device__ __forceinline__ void fma4(float& a, float4 w, float4 f) {
  a = fmaf(w.x, f.x, a);
  a = fmaf(w.y, f.y, a);
  a = fmaf(w.z, f.z, a);
  a = fmaf(w.w, f.w, a);
}

// ---------------------------------------------------------------------------
// K_CTX2: register-tiled GEMM per global relation-chunk (64k x 64j x 256).
// Thread (tk,tj) computes 4x4 tile with k = tk+16a (conflict-free Wn_s reads).
// Epilogue: LDS transpose then tid-linear float4 stores -> one contiguous
// 16KB ctxdot run per block (g-order). Metadata phase resolves the per-edge
// gather source (latest earlier layer touching tail -> compact slot) and
// scatter slot.
// ---------------------------------------------------------------------------
__global__ void __launch_bounds__(256, 4) k_ctx2(
    const float* __restrict__ context, const float* __restrict__ WT2,
    const int* __restrict__ heads, const int* __restrict__ tails,
    const int* __restrict__ sorted, const int4* __restrict__ gchunks,
    const int* __restrict__ gidx, const int* __restrict__ hc,
    const int* __restrict__ slot_lr,
    float* __restrict__ ctxdot, int* __restrict__ m_src,
    int* __restrict__ m_hsl, float* __restrict__ m_invc,
    int* __restrict__ m_g) {
  int4 ck = gchunks[blockIdx.x];
  int r = ck.x, gstart = ck.y, gcnt = ck.z;
  if (gcnt == 0) return;
  int tid = threadIdx.x;
  int tk = tid & 15, tj = tid >> 4;

  __shared__ float4 Wn_s[16 * 64];                 // 16 KB, one 64-d panel of W
  __shared__ __align__(16) float F_s[GCH_][68];    // 17.4 KB gathered ctx panel
  __shared__ int   trow_s[GCH_];
  __shared__ float invc_s[GCH_];

  if (tid < GCH_) {
    int jj = (tid < gcnt) ? tid : (gcnt - 1);
    int pos = gidx[gstart + jj];
    int l = pos >> 12;                             // NEDGE_ = 4096
    int ed = sorted[pos];
    int b = ed >> 7, e = ed & (E_ - 1);
    int t = tails[(b * L_ + l) * E_ + e];
    int h = heads[(b * L_ + l) * E_ + e];
    int trow = b * S_ + t, hrow = b * S_ + h;
    float invc = 1.0f / (float)hc[(size_t)l * BS_ + hrow];   // >= 1
    trow_s[tid] = trow;
    invc_s[tid] = invc;
    if (tid < gcnt) {
      int src = -1;                                // latest l' < l touching tail
      for (int lp = l - 1; lp >= 0; --lp)
        if (hc[(size_t)lp * BS_ + trow] > 0) {
          src = (lp << 12) + slot_lr[(size_t)lp * BS_ + trow];
          break;
        }
      m_src[pos] = src;
      m_hsl[pos] = slot_lr[(size_t)l * BS_ + hrow];
      m_invc[pos] = invc;
      m_g[pos] = gstart + tid;
    }
  }
  __syncthreads();

  float acc[4][4] = {};
  const float4* ctx4 = (const float4*)context;
  const float4* W4 = (const float4*)WT2 + (size_t)r * 80 * 64;

  int jrow = tid >> 2;        // F-staging: 4 threads per edge row
  int c0 = tid & 3;
  int trowj = trow_s[jrow];

  float4 wreg[4], freg[4];
#pragma unroll
  for (int rep = 0; rep < 4; ++rep) {
    wreg[rep] = W4[256 * rep + tid];
    freg[rep] = ctx4[(size_t)trowj * 64 + (c0 + 4 * rep)];
  }

  for (int dp = 0; dp < 4; ++dp) {
    // land staged regs into LDS
#pragma unroll
    for (int rep = 0; rep < 4; ++rep) {
      Wn_s[256 * rep + tid] = wreg[rep];
      *(float4*)&F_s[jrow][4 * (c0 + 4 * rep)] = freg[rep];
    }
    __syncthreads();

    if (dp < 3) {   // issue next panel's loads; hidden under the FMA phase
#pragma unroll
      for (int rep = 0; rep < 4; ++rep) {
        wreg[rep] = W4[1024 * (dp + 1) + 256 * rep + tid];
        freg[rep] = ctx4[(size_t)trowj * 64 + (dp + 1) * 16 + (c0 + 4 * rep)];
      }
    }

#pragma unroll
    for (int i4 = 0; i4 < 16; ++i4) {
      float4 wv[4], fv[4];
#pragma unroll
      for (int a = 0; a < 4; ++a) wv[a] = Wn_s[i4 * 64 + tk + 16 * a];
#pragma unroll
      for (int bb = 0; bb < 4; ++bb)
        fv[bb] = *(const float4*)&F_s[4 * tj + bb][4 * i4];
#pragma unroll
      for (int a = 0; a < 4; ++a)
#pragma unroll
        for (int bb = 0; bb < 4; ++bb) fma4(acc[a][bb], wv[a], fv[bb]);
    }
    __syncthreads();
  }

  // epilogue: scale by invc, transpose through LDS (Wn_s is free), then
  // tid-linear float4 stores -> one contiguous 16KB streaming write.
  float* Tr = (float*)Wn_s;                        // [64][64] j-major
#pragma unroll
  for (int bb = 0; bb < 4; ++bb) {
    int j = 4 * tj + bb;
    float iv = invc_s[j];
#pragma unroll
    for (int a = 0; a < 4; ++a) Tr[j * 64 + tk + 16 * a] = acc[a][bb] * iv;
  }
  __syncthreads();
  float4* dst = (float4*)(ctxdot + (size_t)gstart * DEP_);
  const float4* Tr4 = (const float4*)Tr;
  int n4 = gcnt * 16;
  for (int t = tid; t < n4; t += 256) dst[t] = Tr4[t];
}

// ---------------------------------------------------------------------------
// K_CHAIN: fused 16-layer serial chain, ONE plain launch (320 blocks, co-
// resident at launch_bounds(256,2)). Per layer ONLY the message pass:
// meta (cached) -> 4 coalesced LD_SC gathers from finalized compact layers
// (or 0) -> LDS stage -> 64-wide dot -> +ctxdot -> atomicAdd into own
// layer's compact slot. No copy/zero phases (precomputed indices instead).
// Barrier (r5-proven): arrive[b]=l+1 release; block0 polls -> done=l+1;
// others spin-acquire done. Monotonic, no reset. __syncthreads before
// arrival drains vmcnt (atomics committed before signal).
// ---------------------------------------------------------------------------
__global__ void __launch_bounds__(256, 2) k_chain(
    const float* __restrict__ WT2, const int4* __restrict__ chunks,
    const int* __restrict__ m_src, const int* __restrict__ m_hsl,
    const float* __restrict__ m_invc, const float* __restrict__ ctxdot,
    const int* __restrict__ m_g, float* __restrict__ Acmp,
    int* __restrict__ bar) {
  int tid = threadIdx.x;
  __shared__ float feat[CH_][DEP_];          // 4 KB
  int* done = bar;
  int* arrive = bar + 1;

  for (int l = 0; l < L_; ++l) {
    int4 ck = chunks[l * NCH_ + blockIdx.x];
    int r = ck.x, start = ck.y, ccnt = ck.z;

    if (ccnt > 0) {
      int wv = tid >> 6, k = tid & 63;

      // W child-slice register cache (i4 = 64..79); read-only -> plain
      const float4* Wp = (const float4*)WT2 + ((size_t)r * 80 + 64) * 64 + k;
      float4 w[16];
#pragma unroll
      for (int i = 0; i < 16; ++i) w[i] = Wp[(size_t)i * 64];

      int jj[4], valid[4], srcA[4], hsl[4], gg[4];
      float invc[4];
#pragma unroll
      for (int u = 0; u < 4; ++u) {
        int j = wv + 4 * u;
        valid[u] = (j < ccnt);
        jj[u] = valid[u] ? j : (ccnt - 1);
        int pos = l * NEDGE_ + start + jj[u];
        srcA[u] = m_src[pos];
        hsl[u] = m_hsl[pos];
        invc[u] = m_invc[pos];
        gg[u] = m_g[pos];
      }

      float v[4];
#pragma unroll
      for (int u = 0; u < 4; ++u)
        v[u] = (srcA[u] >= 0) ? LD_SC(&Acmp[(size_t)srcA[u] * DEP_ + k]) : 0.f;
#pragma unroll
      for (int u = 0; u < 4; ++u) feat[jj[u]][k] = v[u];
      __syncthreads();

#pragma unroll
      for (int u = 0; u < 4; ++u) {
        float d = dot64((const float4*)&feat[jj[u]][0], w);
        float contrib = d * invc[u] + ctxdot[(size_t)gg[u] * DEP_ + k];
        if (valid[u])
          atomicAdd(&Acmp[(((size_t)l << 12) + hsl[u]) * DEP_ + k], contrib);
      }
    }

    // ---- grid barrier (skip after last layer; k_out is its own dispatch)
    if (l == L_ - 1) break;
    __syncthreads();   // drains vmcnt for ALL waves -> safe to signal
    if (tid == 0)
      __hip_atomic_store(&arrive[blockIdx.x], l + 1, __ATOMIC_RELEASE,
                         __HIP_MEMORY_SCOPE_AGENT);
    if (blockIdx.x == 0) {
      for (int slot = tid; slot < NCH_; slot += 256)
        while (__hip_atomic_load(&arrive[slot], __ATOMIC_ACQUIRE,
                                 __HIP_MEMORY_SCOPE_AGENT) < l + 1)
          __builtin_amdgcn_s_sleep(1);
      __syncthreads();
      if (tid == 0)
        __hip_atomic_store(done, l + 1, __ATOMIC_RELEASE,
                           __HIP_MEMORY_SCOPE_AGENT);
    } else {
      if (tid == 0)
        while (__hip_atomic_load(done, __ATOMIC_ACQUIRE,
                                 __HIP_MEMORY_SCOPE_AGENT) < l + 1)
          __builtin_amdgcn_s_sleep(1);
    }
    __syncthreads();
  }
}

// ---------------------------------------------------------------------------
// K_O: out = concat(context, childval). Child part: per-row latest touching
// layer (out_l) -> compact slot -> Acmp; never-touched rows = 0.
// Separate launch: kernel boundary gives free coherence.
// ---------------------------------------------------------------------------
__global__ void k_out(const float4* __restrict__ ctx4,
                      const float4* __restrict__ Acmp4,
                      const int* __restrict__ slot_lr,
                      const int* __restrict__ out_l,
                      float4* __restrict__ out4) {
  constexpr int TOT4 = B_ * S_ * (FEAT_ / 4);
  int i = blockIdx.x * blockDim.x + threadIdx.x;
  if (i >= TOT4) return;
  int row = i / 80;
  int c4 = i - row * 80;
  float4 v;
  if (c4 < 64) {
    v = ctx4[(size_t)row * 64 + c4];
  } else {
    int ol = out_l[row];
    if (ol >= 0) {
      int slot = slot_lr[(size_t)ol * BS_ + row];
      v = Acmp4[((size_t)(ol << 12) + slot) * 16 + (c4 - 64)];
    } else {
      v = make_float4(0.f, 0.f, 0.f, 0.f);
    }
  }
  out4[i] = v;
}

extern "C" void kernel_launch(void* const* d_in, const int* in_sizes, int n_in,
                              void* d_out, int out_size, void* d_ws, size_t ws_size,
                              hipStream_t stream) {
  const float* context = (const float*)d_in[0];
  const float* dep_W   = (const float*)d_in[1];
  const int*   heads   = (const int*)d_in[2];
  const int*   tails   = (const int*)d_in[3];
  const int*   rels    = (const int*)d_in[4];
  float* out = (float*)d_out;

  float* ws = (float*)d_ws;
  float* Acmp   = ws;
  float* WT2    = ws + OFF_WT;
  int*   sorted = (int*)(ws + OFF_SORT);
  int4*  chunks = (int4*)(ws + OFF_CHUNK);
  int*   hc     = (int*)(ws + OFF_HC);
  int*   m_src  = (int*)(ws + OFF_MS);
  int*   m_hsl  = (int*)(ws + OFF_MH);
  float* m_invc = ws + OFF_MI;
  float* ctxdot = ws + OFF_CD;
  int*   gidx   = (int*)(ws + OFF_GIDX);
  int4*  gchunks= (int4*)(ws + OFF_GCH);
  int*   hist_lr= (int*)(ws + OFF_HLR);
  int*   start_lr=(int*)(ws + OFF_SLR);
  int*   m_g    = (int*)(ws + OFF_MG);
  int*   slot_lr= (int*)(ws + OFF_SLOT);
  int*   out_l  = (int*)(ws + OFF_OL);
  int*   bar    = (int*)(ws + OFF_BAR);

  k_pre<<<L_ + PREB_, 256, 0, stream>>>(dep_W, rels, heads, WT2, sorted,
                                        chunks, hc, Acmp, hist_lr, start_lr,
                                        out_l, bar);

  k_gidx<<<R_ * L_ + L_, 256, 0, stream>>>(hist_lr, start_lr, hc, gidx,
                                           gchunks, slot_lr, out_l);

  k_ctx2<<<NGC_, 256, 0, stream>>>(context, WT2, heads, tails, sorted,
                                   gchunks, gidx, hc, slot_lr, ctxdot,
                                   m_src, m_hsl, m_invc, m_g);

  k_chain<<<NCH_, 256, 0, stream>>>(WT2, chunks, m_src, m_hsl, m_invc,
                                    ctxdot, m_g, Acmp, bar);

  constexpr int TOT4 = B_ * S_ * (FEAT_ / 4);
  k_out<<<(TOT4 + 255) / 256, 256, 0, stream>>>(
      (const float4*)context, (const float4*)Acmp, slot_lr, out_l,
      (float4*)out);
}

// Round 7
// 419.811 us; speedup vs baseline: 2.0209x; 2.0209x over previous
//
#include <hip/hip_runtime.h>

// Problem constants: B,S,NODE,DEP,R,L,E = 32,1024,256,64,50,16,128
constexpr int B_ = 32;
constexpr int S_ = 1024;
constexpr int NODE_ = 256;
constexpr int DEP_ = 64;
constexpr int R_ = 50;
constexpr int L_ = 16;
constexpr int E_ = 128;
constexpr int FEAT_ = NODE_ + DEP_;     // 320
constexpr int NEDGE_ = B_ * E_;         // 4096 edges per layer
constexpr int BS_ = B_ * S_;            // 32768 rows
constexpr int CH_ = 16;                 // edges per relation-chunk (chain)
constexpr int NCH_ = 320;               // sum ceil(n_r/16) <= 306
constexpr int PREB_ = 512;              // worker blocks in k_pre
constexpr int GCH_ = 64;                // edges per GLOBAL relation-chunk (k_ctx2)
constexpr int NGC_ = 1088;              // >= 50 + 65536/64 = 1074
constexpr int SLOTCAP_ = 4096;          // max touched rows per layer (<= NEDGE_)

// ---------------------------------------------------------------------------
// Key algebra: msg = W[r][:,0:256]@ctx[t] + W[r][:,256:320]@childval[t].
// ctx term + index metadata precomputed in k_ctx2 (relation-binned ACROSS
// layers -> 64x64x256 register-tiled GEMM per block; ctxdot in g-order).
// Per-layer COMPACT accumulators Acmp[l][slot][64]; per-edge gather/scatter
// indices fully precomputed (m_src latest-earlier-layer slot / m_hsl / out_l).
// r6 post-mortem: the fused chain's 37us/layer was NOT data work (traffic
// dropped 3x, time didn't) - it was the barrier's ACQUIRE/RELEASE agent ops:
// on gfx950 agent-acquire = bulk L2 invalidate, agent-release = L2 writeback.
// 320 spinning block-leaders = continuous whole-L2 invalidation storm on all
// XCDs, every layer (also evicting cached W/meta between layers).
// r7: barrier uses ONLY relaxed PoC-direct (sc0 sc1) flag ops - zero cache
// maintenance. Ordering: __syncthreads() drains vmcnt (atomicAdds committed
// at PoC) before the flag store; spin exit control-depends on the flag; all
// data gathers are PoC-direct relaxed (r4-proven). Flattened: every block's
// wave 0 polls all 320 flags directly (lane t: 5 flags) - no done-flag hop.
// ---------------------------------------------------------------------------
constexpr size_t N_ACMP   = (size_t)L_ * SLOTCAP_ * DEP_;    // 4,194,304 floats
constexpr size_t OFF_WT   = N_ACMP;
constexpr size_t N_WT     = (size_t)R_ * FEAT_ * DEP_;       // 1,024,000
constexpr size_t OFF_SORT = OFF_WT + N_WT;
constexpr size_t N_SORT   = (size_t)L_ * NEDGE_;             // 65,536 ints
constexpr size_t OFF_CHUNK= OFF_SORT + N_SORT;
constexpr size_t N_CHUNK_I= (size_t)L_ * NCH_ * 4;           // ints
constexpr size_t OFF_HC   = OFF_CHUNK + N_CHUNK_I;
constexpr size_t N_HC     = (size_t)L_ * BS_;                // 524,288 ints
constexpr size_t OFF_MS   = OFF_HC + N_HC;                   // m_src
constexpr size_t OFF_MH   = OFF_MS + N_SORT;                 // m_hsl
constexpr size_t OFF_MI   = OFF_MH + N_SORT;                 // m_invc
constexpr size_t OFF_CD   = OFF_MI + N_SORT;                 // ctxdot (g-order)
constexpr size_t N_CD     = (size_t)L_ * NEDGE_ * DEP_;      // 4,194,304
constexpr size_t OFF_GIDX = OFF_CD + N_CD;                   // global bin: pos list
constexpr size_t OFF_GCH  = OFF_GIDX + N_SORT;               // int4 * NGC_
constexpr size_t OFF_HLR  = OFF_GCH + (size_t)NGC_ * 4;      // hist_lr [L*R] ints
constexpr size_t OFF_SLR  = OFF_HLR + (size_t)L_ * R_;       // start_lr [L*R] ints
constexpr size_t OFF_MG   = OFF_SLR + (size_t)L_ * R_;       // m_g: pos -> g
constexpr size_t OFF_SLOT = OFF_MG + N_SORT;                 // slot_lr [L][BS]
constexpr size_t OFF_OL   = OFF_SLOT + (size_t)L_ * BS_;     // out_l [BS]
constexpr size_t OFF_BAR  = OFF_OL + BS_;                    // arrive[NCH_]

#define LD_SC(p)    __hip_atomic_load((p), __ATOMIC_RELAXED, __HIP_MEMORY_SCOPE_AGENT)
#define ST_SC(p, v) __hip_atomic_store((p), (v), __ATOMIC_RELAXED, __HIP_MEMORY_SCOPE_AGENT)

// ---------------------------------------------------------------------------
// K_PRE: blocks 0..15 = per-layer relation binning + chunk table + head-count
// hist (publishes hist/start tables); blocks 16.. = W re-layout
// WT2[r][i4][k][c] + zero Acmp + out_l=-1 + barrier flags.
// ---------------------------------------------------------------------------
__global__ void k_pre(const float* __restrict__ W, const int* __restrict__ rels,
                      const int* __restrict__ heads,
                      float* __restrict__ WT2, int* __restrict__ sorted,
                      int4* __restrict__ chunks, int* __restrict__ hc,
                      float* __restrict__ Acmp,
                      int* __restrict__ hist_lr, int* __restrict__ start_lr,
                      int* __restrict__ out_l, int* __restrict__ bar) {
  int blk = blockIdx.x, tid = threadIdx.x;
  if (blk < L_) {
    int l = blk;
    __shared__ int hist[R_], startA[R_], rank[R_], cstart[R_];
    __shared__ int ntot;
    if (tid < R_) { hist[tid] = 0; rank[tid] = 0; }
    int* hcl = hc + (size_t)l * BS_;
    for (int i = tid; i < BS_; i += 256) hcl[i] = 0;
    __syncthreads();
    for (int ed = tid; ed < NEDGE_; ed += 256) {
      int b = ed >> 7, e = ed & (E_ - 1);
      atomicAdd(&hist[rels[(b * L_ + l) * E_ + e]], 1);
      atomicAdd(&hcl[b * S_ + heads[(b * L_ + l) * E_ + e]], 1);
    }
    __syncthreads();
    if (tid == 0) {
      int s = 0, cs = 0;
      for (int r = 0; r < R_; ++r) {
        startA[r] = s; s += hist[r];
        cstart[r] = cs; cs += (hist[r] + CH_ - 1) / CH_;
      }
      ntot = cs;
    }
    __syncthreads();
    for (int ed = tid; ed < NEDGE_; ed += 256) {
      int b = ed >> 7, e = ed & (E_ - 1);
      int r = rels[(b * L_ + l) * E_ + e];
      int pos = startA[r] + atomicAdd(&rank[r], 1);
      sorted[l * NEDGE_ + pos] = ed;
    }
    if (tid < R_) {
      hist_lr[l * R_ + tid] = hist[tid];
      start_lr[l * R_ + tid] = startA[tid];
      int n = hist[tid], st = startA[tid], cs = cstart[tid];
      for (int m = 0; m * CH_ < n; ++m) {
        int c = n - m * CH_; if (c > CH_) c = CH_;
        chunks[l * NCH_ + cs + m] = make_int4(tid, st + m * CH_, c, 0);
      }
    }
    __syncthreads();
    for (int i = ntot + tid; i < NCH_; i += 256)
      chunks[l * NCH_ + i] = make_int4(0, 0, 0, 0);
  } else {
    int gtid = (blk - L_) * 256 + tid;
    const int NT = PREB_ * 256;
    for (int i = gtid; i < NCH_; i += NT) bar[i] = 0;   // arrive[]
    for (int i = gtid; i < BS_; i += NT) out_l[i] = -1;
    for (int gid = gtid; gid < (int)N_WT; gid += NT) {
      int r = gid / 20480;           // 80*64*4
      int rem = gid - r * 20480;
      int i4 = rem >> 8;
      int k = (rem >> 2) & 63;
      int c = rem & 3;
      WT2[gid] = W[((size_t)r * DEP_ + k) * FEAT_ + 4 * i4 + c];
    }
    float4* z4 = (float4*)Acmp;
    int nz4 = (int)(N_ACMP / 4);
    for (int i = gtid; i < nz4; i += NT) z4[i] = make_float4(0.f, 0.f, 0.f, 0.f);
  }
}

// ---------------------------------------------------------------------------
// K_GIDX: blocks 0..799 = one per (r,l) run: redundantly compute global
// r-grouped offsets from the hist table, copy the run into gidx; block 0
// also emits the global chunk table. Blocks 800..815 = one per layer:
// dense slot ranks (slot_lr[l][row] = rank among touched rows) + per-row
// latest-touching-layer via atomicMax(out_l).
// ---------------------------------------------------------------------------
__global__ void __launch_bounds__(256) k_gidx(
    const int* __restrict__ hist_lr, const int* __restrict__ start_lr,
    const int* __restrict__ hc,
    int* __restrict__ gidx, int4* __restrict__ gchunks,
    int* __restrict__ slot_lr, int* __restrict__ out_l) {
  int bid = blockIdx.x, tid = threadIdx.x;
  if (bid >= R_ * L_) {
    // --- slot-rank blocks: one per layer ---
    int l = bid - R_ * L_;
    const int* hcl = hc + (size_t)l * BS_;
    int* sl = slot_lr + (size_t)l * BS_;
    __shared__ int psum[256];
    constexpr int RPT = BS_ / 256;       // 128 rows per thread
    int r0 = tid * RPT;
    int cnt = 0;
    for (int i = 0; i < RPT; ++i) cnt += (hcl[r0 + i] > 0) ? 1 : 0;
    psum[tid] = cnt;
    __syncthreads();
    if (tid == 0) {
      int s = 0;
      for (int i = 0; i < 256; ++i) { int c = psum[i]; psum[i] = s; s += c; }
    }
    __syncthreads();
    int base = psum[tid];
    for (int i = 0; i < RPT; ++i) {
      int row = r0 + i;
      if (hcl[row] > 0) { sl[row] = base++; atomicMax(&out_l[row], l); }
    }
    return;
  }
  int r = bid / L_, l = bid - r * L_;
  __shared__ int sh[L_ * R_];
  __shared__ int base_s, ntot_s;
  for (int i = tid; i < L_ * R_; i += 256) sh[i] = hist_lr[i];
  __syncthreads();
  if (tid == 0) {
    int goff = 0;
    for (int rr = 0; rr < r; ++rr)
      for (int ll = 0; ll < L_; ++ll) goff += sh[ll * R_ + rr];
    for (int ll = 0; ll < l; ++ll) goff += sh[ll * R_ + r];
    base_s = goff;
  }
  __syncthreads();
  int n = sh[l * R_ + r];
  int st = start_lr[l * R_ + r];
  int base = base_s;
  for (int i = tid; i < n; i += 256)
    gidx[base + i] = l * NEDGE_ + st + i;

  if (bid == 0) {
    __shared__ int tot[R_], goffA[R_], cstart[R_];
    if (tid < R_) {
      int t = 0;
      for (int ll = 0; ll < L_; ++ll) t += sh[ll * R_ + tid];
      tot[tid] = t;
    }
    __syncthreads();
    if (tid == 0) {
      int s = 0, cs = 0;
      for (int rr = 0; rr < R_; ++rr) {
        goffA[rr] = s; s += tot[rr];
        cstart[rr] = cs; cs += (tot[rr] + GCH_ - 1) / GCH_;
      }
      ntot_s = cs;
    }
    __syncthreads();
    if (tid < R_) {
      int nn = tot[tid], go = goffA[tid], cs = cstart[tid];
      for (int m = 0; m * GCH_ < nn; ++m) {
        int c = nn - m * GCH_; if (c > GCH_) c = GCH_;
        gchunks[cs + m] = make_int4(tid, go + m * GCH_, c, 0);
      }
    }
    __syncthreads();
    for (int i = ntot_s + tid; i < NGC_; i += 256)
      gchunks[i] = make_int4(0, 0, 0, 0);
  }
}

__device__ __forceinline__ float dot64(const float4* __restrict__ f4,
                                       const float4* __restrict__ w) {
  float a0 = 0.f, a1 = 0.f, a2 = 0.f, a3 = 0.f;
#pragma unroll
  for (int i = 0; i < 16; ++i) {
    float4 f = f4[i];
    a0 = fmaf(w[i].x, f.x, a0);
    a1 = fmaf(w[i].y, f.y, a1);
    a2 = fmaf(w[i].z, f.z, a2);
    a3 = fmaf(w[i].w, f.w, a3);
  }
  return (a0 + a1) + (a2 + a3);
}

__device__ __forceinline__ void fma4(float& a, float4 w, float4 f) {
  a = fmaf(w.x, f.x, a);
  a = fmaf(w.y, f.y, a);
  a = fmaf(w.z, f.z, a);
  a = fmaf(w.w, f.w, a);
}

// ---------------------------------------------------------------------------
// K_CTX2: register-tiled GEMM per global relation-chunk (64k x 64j x 256).
// Thread (tk,tj) computes 4x4 tile with k = tk+16a (conflict-free Wn_s reads).
// Epilogue: LDS transpose then tid-linear float4 stores -> one contiguous
// 16KB ctxdot run per block (g-order). Metadata phase resolves the per-edge
// gather source (latest earlier layer touching tail -> compact slot) and
// scatter slot.
// ---------------------------------------------------------------------------
__global__ void __launch_bounds__(256, 4) k_ctx2(
    const float* __restrict__ context, const float* __restrict__ WT2,
    const int* __restrict__ heads, const int* __restrict__ tails,
    const int* __restrict__ sorted, const int4* __restrict__ gchunks,
    const int* __restrict__ gidx, const int* __restrict__ hc,
    const int* __restrict__ slot_lr,
    float* __restrict__ ctxdot, int* __restrict__ m_src,
    int* __restrict__ m_hsl, float* __restrict__ m_invc,
    int* __restrict__ m_g) {
  int4 ck = gchunks[blockIdx.x];
  int r = ck.x, gstart = ck.y, gcnt = ck.z;
  if (gcnt == 0) return;
  int tid = threadIdx.x;
  int tk = tid & 15, tj = tid >> 4;

  __shared__ float4 Wn_s[16 * 64];                 // 16 KB, one 64-d panel of W
  __shared__ __align__(16) float F_s[GCH_][68];    // 17.4 KB gathered ctx panel
  __shared__ int   trow_s[GCH_];
  __shared__ float invc_s[GCH_];

  if (tid < GCH_) {
    int jj = (tid < gcnt) ? tid : (gcnt - 1);
    int pos = gidx[gstart + jj];
    int l = pos >> 12;                             // NEDGE_ = 4096
    int ed = sorted[pos];
    int b = ed >> 7, e = ed & (E_ - 1);
    int t = tails[(b * L_ + l) * E_ + e];
    int h = heads[(b * L_ + l) * E_ + e];
    int trow = b * S_ + t, hrow = b * S_ + h;
    float invc = 1.0f / (float)hc[(size_t)l * BS_ + hrow];   // >= 1
    trow_s[tid] = trow;
    invc_s[tid] = invc;
    if (tid < gcnt) {
      int src = -1;                                // latest l' < l touching tail
      for (int lp = l - 1; lp >= 0; --lp)
        if (hc[(size_t)lp * BS_ + trow] > 0) {
          src = (lp << 12) + slot_lr[(size_t)lp * BS_ + trow];
          break;
        }
      m_src[pos] = src;
      m_hsl[pos] = slot_lr[(size_t)l * BS_ + hrow];
      m_invc[pos] = invc;
      m_g[pos] = gstart + tid;
    }
  }
  __syncthreads();

  float acc[4][4] = {};
  const float4* ctx4 = (const float4*)context;
  const float4* W4 = (const float4*)WT2 + (size_t)r * 80 * 64;

  int jrow = tid >> 2;        // F-staging: 4 threads per edge row
  int c0 = tid & 3;
  int trowj = trow_s[jrow];

  float4 wreg[4], freg[4];
#pragma unroll
  for (int rep = 0; rep < 4; ++rep) {
    wreg[rep] = W4[256 * rep + tid];
    freg[rep] = ctx4[(size_t)trowj * 64 + (c0 + 4 * rep)];
  }

  for (int dp = 0; dp < 4; ++dp) {
    // land staged regs into LDS
#pragma unroll
    for (int rep = 0; rep < 4; ++rep) {
      Wn_s[256 * rep + tid] = wreg[rep];
      *(float4*)&F_s[jrow][4 * (c0 + 4 * rep)] = freg[rep];
    }
    __syncthreads();

    if (dp < 3) {   // issue next panel's loads; hidden under the FMA phase
#pragma unroll
      for (int rep = 0; rep < 4; ++rep) {
        wreg[rep] = W4[1024 * (dp + 1) + 256 * rep + tid];
        freg[rep] = ctx4[(size_t)trowj * 64 + (dp + 1) * 16 + (c0 + 4 * rep)];
      }
    }

#pragma unroll
    for (int i4 = 0; i4 < 16; ++i4) {
      float4 wv[4], fv[4];
#pragma unroll
      for (int a = 0; a < 4; ++a) wv[a] = Wn_s[i4 * 64 + tk + 16 * a];
#pragma unroll
      for (int bb = 0; bb < 4; ++bb)
        fv[bb] = *(const float4*)&F_s[4 * tj + bb][4 * i4];
#pragma unroll
      for (int a = 0; a < 4; ++a)
#pragma unroll
        for (int bb = 0; bb < 4; ++bb) fma4(acc[a][bb], wv[a], fv[bb]);
    }
    __syncthreads();
  }

  // epilogue: scale by invc, transpose through LDS (Wn_s is free), then
  // tid-linear float4 stores -> one contiguous 16KB streaming write.
  float* Tr = (float*)Wn_s;                        // [64][64] j-major
#pragma unroll
  for (int bb = 0; bb < 4; ++bb) {
    int j = 4 * tj + bb;
    float iv = invc_s[j];
#pragma unroll
    for (int a = 0; a < 4; ++a) Tr[j * 64 + tk + 16 * a] = acc[a][bb] * iv;
  }
  __syncthreads();
  float4* dst = (float4*)(ctxdot + (size_t)gstart * DEP_);
  const float4* Tr4 = (const float4*)Tr;
  int n4 = gcnt * 16;
  for (int t = tid; t < n4; t += 256) dst[t] = Tr4[t];
}

// ---------------------------------------------------------------------------
// K_CHAIN: fused 16-layer serial chain, ONE plain launch (320 blocks, co-
// resident at launch_bounds(256,2)). Per layer ONLY the message pass:
// meta (cached) -> 4 coalesced LD_SC gathers from finalized compact layers
// (or 0) -> LDS stage -> 64-wide dot -> +ctxdot -> atomicAdd into own
// layer's compact slot.
// Barrier v3: ALL-RELAXED PoC flags (no acquire/release -> no bulk L2
// invalidate/writeback storms, the r6-diagnosed 30+us/layer cost).
//   __syncthreads()  (drains each wave's vmcnt -> adds committed at PoC)
//   tid0: ST_SC arrive[b] = l+1            (PoC-direct store)
//   wave0: poll all 320 flags (lane t: t, t+64, ..., 5 each), __all >= l+1
//   __syncthreads()  (compiler + execution fence for next layer)
// ---------------------------------------------------------------------------
__global__ void __launch_bounds__(256, 2) k_chain(
    const float* __restrict__ WT2, const int4* __restrict__ chunks,
    const int* __restrict__ m_src, const int* __restrict__ m_hsl,
    const float* __restrict__ m_invc, const float* __restrict__ ctxdot,
    const int* __restrict__ m_g, float* __restrict__ Acmp,
    int* __restrict__ arrive) {
  int tid = threadIdx.x;
  __shared__ float feat[CH_][DEP_];          // 4 KB

  for (int l = 0; l < L_; ++l) {
    int4 ck = chunks[l * NCH_ + blockIdx.x];
    int r = ck.x, start = ck.y, ccnt = ck.z;

    if (ccnt > 0) {
      int wv = tid >> 6, k = tid & 63;

      // W child-slice register cache (i4 = 64..79); read-only -> plain
      const float4* Wp = (const float4*)WT2 + ((size_t)r * 80 + 64) * 64 + k;
      float4 w[16];
#pragma unroll
      for (int i = 0; i < 16; ++i) w[i] = Wp[(size_t)i * 64];

      int jj[4], valid[4], srcA[4], hsl[4], gg[4];
      float invc[4];
#pragma unroll
      for (int u = 0; u < 4; ++u) {
        int j = wv + 4 * u;
        valid[u] = (j < ccnt);
        jj[u] = valid[u] ? j : (ccnt - 1);
        int pos = l * NEDGE_ + start + jj[u];
        srcA[u] = m_src[pos];
        hsl[u] = m_hsl[pos];
        invc[u] = m_invc[pos];
        gg[u] = m_g[pos];
      }

      float v[4];
#pragma unroll
      for (int u = 0; u < 4; ++u)
        v[u] = (srcA[u] >= 0) ? LD_SC(&Acmp[(size_t)srcA[u] * DEP_ + k]) : 0.f;
#pragma unroll
      for (int u = 0; u < 4; ++u) feat[jj[u]][k] = v[u];
      __syncthreads();

#pragma unroll
      for (int u = 0; u < 4; ++u) {
        float d = dot64((const float4*)&feat[jj[u]][0], w);
        float contrib = d * invc[u] + ctxdot[(size_t)gg[u] * DEP_ + k];
        if (valid[u])
          atomicAdd(&Acmp[(((size_t)l << 12) + hsl[u]) * DEP_ + k], contrib);
      }
    }

    // ---- grid barrier v3 (all-relaxed PoC flags; skip after last layer)
    if (l == L_ - 1) break;
    __syncthreads();   // drains vmcnt for ALL waves -> adds committed at PoC
    if (tid == 0)
      ST_SC(&arrive[blockIdx.x], l + 1);
    if (tid < 64) {
      for (;;) {
        int m0 = LD_SC(&arrive[tid]);
        int m1 = LD_SC(&arrive[tid + 64]);
        int m2 = LD_SC(&arrive[tid + 128]);
        int m3 = LD_SC(&arrive[tid + 192]);
        int m4 = LD_SC(&arrive[tid + 256]);
        int m = min(min(min(m0, m1), min(m2, m3)), m4);
        if (__all(m >= l + 1)) break;
        __builtin_amdgcn_s_sleep(2);
      }
    }
    __syncthreads();
  }
}

// ---------------------------------------------------------------------------
// K_O: out = concat(context, childval). Child part: per-row latest touching
// layer (out_l) -> compact slot -> Acmp; never-touched rows = 0.
// Separate launch: kernel boundary gives free coherence.
// ---------------------------------------------------------------------------
__global__ void k_out(const float4* __restrict__ ctx4,
                      const float4* __restrict__ Acmp4,
                      const int* __restrict__ slot_lr,
                      const int* __restrict__ out_l,
                      float4* __restrict__ out4) {
  constexpr int TOT4 = B_ * S_ * (FEAT_ / 4);
  int i = blockIdx.x * blockDim.x + threadIdx.x;
  if (i >= TOT4) return;
  int row = i / 80;
  int c4 = i - row * 80;
  float4 v;
  if (c4 < 64) {
    v = ctx4[(size_t)row * 64 + c4];
  } else {
    int ol = out_l[row];
    if (ol >= 0) {
      int slot = slot_lr[(size_t)ol * BS_ + row];
      v = Acmp4[((size_t)(ol << 12) + slot) * 16 + (c4 - 64)];
    } else {
      v = make_float4(0.f, 0.f, 0.f, 0.f);
    }
  }
  out4[i] = v;
}

extern "C" void kernel_launch(void* const* d_in, const int* in_sizes, int n_in,
                              void* d_out, int out_size, void* d_ws, size_t ws_size,
                              hipStream_t stream) {
  const float* context = (const float*)d_in[0];
  const float* dep_W   = (const float*)d_in[1];
  const int*   heads   = (const int*)d_in[2];
  const int*   tails   = (const int*)d_in[3];
  const int*   rels    = (const int*)d_in[4];
  float* out = (float*)d_out;

  float* ws = (float*)d_ws;
  float* Acmp   = ws;
  float* WT2    = ws + OFF_WT;
  int*   sorted = (int*)(ws + OFF_SORT);
  int4*  chunks = (int4*)(ws + OFF_CHUNK);
  int*   hc     = (int*)(ws + OFF_HC);
  int*   m_src  = (int*)(ws + OFF_MS);
  int*   m_hsl  = (int*)(ws + OFF_MH);
  float* m_invc = ws + OFF_MI;
  float* ctxdot = ws + OFF_CD;
  int*   gidx   = (int*)(ws + OFF_GIDX);
  int4*  gchunks= (int4*)(ws + OFF_GCH);
  int*   hist_lr= (int*)(ws + OFF_HLR);
  int*   start_lr=(int*)(ws + OFF_SLR);
  int*   m_g    = (int*)(ws + OFF_MG);
  int*   slot_lr= (int*)(ws + OFF_SLOT);
  int*   out_l  = (int*)(ws + OFF_OL);
  int*   bar    = (int*)(ws + OFF_BAR);

  k_pre<<<L_ + PREB_, 256, 0, stream>>>(dep_W, rels, heads, WT2, sorted,
                                        chunks, hc, Acmp, hist_lr, start_lr,
                                        out_l, bar);

  k_gidx<<<R_ * L_ + L_, 256, 0, stream>>>(hist_lr, start_lr, hc, gidx,
                                           gchunks, slot_lr, out_l);

  k_ctx2<<<NGC_, 256, 0, stream>>>(context, WT2, heads, tails, sorted,
                                   gchunks, gidx, hc, slot_lr, ctxdot,
                                   m_src, m_hsl, m_invc, m_g);

  k_chain<<<NCH_, 256, 0, stream>>>(WT2, chunks, m_src, m_hsl, m_invc,
                                    ctxdot, m_g, Acmp, bar);

  constexpr int TOT4 = B_ * S_ * (FEAT_ / 4);
  k_out<<<(TOT4 + 255) / 256, 256, 0, stream>>>(
      (const float4*)context, (const float4*)Acmp, slot_lr, out_l,
      (float4*)out);
}